// Round 1
// baseline (38001.083 us; speedup 1.0000x reference)
//
#include <hip/hip_runtime.h>
#include <hip/hip_bf16.h>
#include <math.h>

// Problem constants (fixed by setup_inputs)
#define V_   2
#define B_   8
#define S_   2048
#define D_   512
#define VOCAB_ 8192
#define STEPS_ 16
#define DECAY_ 0.999f
#define EPS_ 1e-6f
#define VB_  (V_ * B_)       // 16
#define R_   (VB_ * S_)      // 32768 token rows
#define RD_  ((long)R_ * D_) // 16777216 floats

enum Act { ACT_IDENT = 0, ACT_SIGMOID = 1, ACT_GELU = 2, ACT_PHI = 3 };

template <int ACT>
__device__ __forceinline__ float act_fn(float x) {
    if (ACT == ACT_SIGMOID) return 1.0f / (1.0f + __expf(-x));
    if (ACT == ACT_GELU)    return 0.5f * x * (1.0f + erff(x * 0.70710678118654752f));
    if (ACT == ACT_PHI)     return x > 0.0f ? x + 1.0f : __expf(x);  // elu(x)+1
    return x;
}

// ---------------------------------------------------------------------------
// Generic fp32 GEMM: C = beta*C + Gate? ⊙ (alpha * act(A·B))
//   A: M×K row-major (or K×M if TRANS_A — used for K^T·V)
//   B: K×N row-major
// 128×128 block, BK=8, 256 threads, 8×8 microtile. M%128==0, N%128==0, K%8==0.
// ---------------------------------------------------------------------------
template <int ACT, bool HAS_GATE, bool TRANS_A>
__launch_bounds__(256)
__global__ void gemm_kernel(const float* __restrict__ A, const float* __restrict__ B,
                            float* __restrict__ C, const float* __restrict__ Gate,
                            int M, int N, int K,
                            long sA, long sB, long sC,
                            float alpha, float beta) {
    __shared__ float As[8][128];
    __shared__ float Bs[8][128];
    const int bz = blockIdx.z;
    A += (long)bz * sA;
    B += (long)bz * sB;
    C += (long)bz * sC;

    const int rowBase = blockIdx.x * 128;
    const int colBase = blockIdx.y * 128;
    const int t  = threadIdx.x;
    const int ty = t >> 4;        // 0..15
    const int tx = t & 15;        // 0..15

    // staging indices: 8×128 tile, one float4 per thread
    const int bkr = t >> 5;         // 0..7   (k within tile)
    const int bkc = (t & 31) * 4;   // 0..124 (col within tile)
    // A (non-transposed): 128×8 tile, one float4 per thread
    const int ar = t >> 1;          // 0..127 (row)
    const int ac = (t & 1) * 4;     // 0 or 4 (k)

    float acc[8][8];
#pragma unroll
    for (int i = 0; i < 8; i++)
#pragma unroll
        for (int j = 0; j < 8; j++) acc[i][j] = 0.0f;

    for (int k0 = 0; k0 < K; k0 += 8) {
        float4 bv = *(const float4*)&B[(long)(k0 + bkr) * N + colBase + bkc];
        float4 av;
        if (TRANS_A)
            av = *(const float4*)&A[(long)(k0 + bkr) * M + rowBase + bkc];
        else
            av = *(const float4*)&A[(long)(rowBase + ar) * K + k0 + ac];
        __syncthreads();  // prior tile consumed
        if (TRANS_A) {
            *(float4*)&As[bkr][bkc] = av;
        } else {
            As[ac + 0][ar] = av.x;
            As[ac + 1][ar] = av.y;
            As[ac + 2][ar] = av.z;
            As[ac + 3][ar] = av.w;
        }
        *(float4*)&Bs[bkr][bkc] = bv;
        __syncthreads();
#pragma unroll
        for (int kk = 0; kk < 8; kk++) {
            float a0[8], b0[8];
            *(float4*)&a0[0] = *(const float4*)&As[kk][ty * 8];
            *(float4*)&a0[4] = *(const float4*)&As[kk][ty * 8 + 4];
            *(float4*)&b0[0] = *(const float4*)&Bs[kk][tx * 8];
            *(float4*)&b0[4] = *(const float4*)&Bs[kk][tx * 8 + 4];
#pragma unroll
            for (int i = 0; i < 8; i++)
#pragma unroll
                for (int j = 0; j < 8; j++)
                    acc[i][j] = fmaf(a0[i], b0[j], acc[i][j]);
        }
    }

#pragma unroll
    for (int i = 0; i < 8; i++) {
        const long r = rowBase + ty * 8 + i;
        const long base = r * (long)N + colBase + tx * 8;
#pragma unroll
        for (int jj = 0; jj < 8; jj += 4) {
            float4 res;
            res.x = alpha * act_fn<ACT>(acc[i][jj + 0]);
            res.y = alpha * act_fn<ACT>(acc[i][jj + 1]);
            res.z = alpha * act_fn<ACT>(acc[i][jj + 2]);
            res.w = alpha * act_fn<ACT>(acc[i][jj + 3]);
            if (HAS_GATE) {
                float4 gv = *(const float4*)&Gate[base + jj];
                res.x *= gv.x; res.y *= gv.y; res.z *= gv.z; res.w *= gv.w;
            }
            if (beta != 0.0f) {
                float4 cv = *(const float4*)&C[base + jj];
                res.x += beta * cv.x; res.y += beta * cv.y;
                res.z += beta * cv.z; res.w += beta * cv.w;
            }
            *(float4*)&C[base + jj] = res;
        }
    }
}

// ---------------------------------------------------------------------------
// RMS norm over last dim (D=512). One block (128 thr × float4) per row.
// Safe in-place (each thread reads exactly what it later writes).
// ---------------------------------------------------------------------------
__launch_bounds__(128)
__global__ void rms_kernel(const float* __restrict__ X, float* __restrict__ Y) {
    const long row = blockIdx.x;
    const float4 v = *(const float4*)&X[row * D_ + threadIdx.x * 4];
    float ss = v.x * v.x + v.y * v.y + v.z * v.z + v.w * v.w;
#pragma unroll
    for (int off = 32; off > 0; off >>= 1) ss += __shfl_down(ss, off, 64);
    __shared__ float s2[2];
    if ((threadIdx.x & 63) == 0) s2[threadIdx.x >> 6] = ss;
    __syncthreads();
    const float tot = s2[0] + s2[1];
    const float sc = rsqrtf(tot * (1.0f / (float)D_) + EPS_);
    float4 o;
    o.x = v.x * sc; o.y = v.y * sc; o.z = v.z * sc; o.w = v.w * sc;
    *(float4*)&Y[row * D_ + threadIdx.x * 4] = o;
}

// ---------------------------------------------------------------------------
// Embedding gather: state[(v*B+b)*S+s, :] = emb[v, inputs[b,s], :]
// One block (128 thr × float4) per token row.
// ---------------------------------------------------------------------------
__launch_bounds__(128)
__global__ void embed_kernel(const int* __restrict__ inputs, const float* __restrict__ emb,
                             float* __restrict__ state) {
    const int row = blockIdx.x;       // vb*S + s
    const int s  = row & (S_ - 1);
    const int vb = row >> 11;         // S_ = 2^11
    const int b  = vb & (B_ - 1);
    const int v  = vb >> 3;           // B_ = 2^3
    const int tok = inputs[b * S_ + s];
    const float4 val = *(const float4*)&emb[((long)v * VOCAB_ + tok) * D_ + threadIdx.x * 4];
    *(float4*)&state[(long)row * D_ + threadIdx.x * 4] = val;
}

// ---------------------------------------------------------------------------
// View-mean over V=2: comb[e] = 0.5*(state[e] + state[e + B*S*D]) for e < B*S*D
// ---------------------------------------------------------------------------
__launch_bounds__(256)
__global__ void combine_kernel(const float* __restrict__ state, float* __restrict__ comb) {
    const long i = (long)blockIdx.x * 256 + threadIdx.x;  // float4 index
    const float4 a = ((const float4*)state)[i];
    const float4 c = ((const float4*)(state + (long)B_ * S_ * D_))[i];
    float4 o;
    o.x = 0.5f * (a.x + c.x); o.y = 0.5f * (a.y + c.y);
    o.z = 0.5f * (a.z + c.z); o.w = 0.5f * (a.w + c.w);
    ((float4*)comb)[i] = o;
}

extern "C" void kernel_launch(void* const* d_in, const int* in_sizes, int n_in,
                              void* d_out, int out_size, void* d_ws, size_t ws_size,
                              hipStream_t stream) {
    const int*   inputs = (const int*)d_in[0];
    const float* emb = (const float*)d_in[1];
    const float* Wg  = (const float*)d_in[2];
    const float* Wu  = (const float*)d_in[3];
    const float* Wd  = (const float*)d_in[4];
    const float* Wq  = (const float*)d_in[5];
    const float* Wk  = (const float*)d_in[6];
    const float* Wv  = (const float*)d_in[7];
    const float* Wv_o = (const float*)d_in[8];
    const float* Wlm = (const float*)d_in[9];
    float* out = (float*)d_out;

    float* ws    = (float*)d_ws;
    float* state = ws;               // R_*D_ (16M floats)
    float* nbuf  = ws + 1 * RD_;     // n / n2 / mixed
    float* gbuf  = ws + 2 * RD_;     // gate; reused for combined
    float* ubuf  = ws + 3 * RD_;     // R_*2D_ (32M floats)
    float* qbuf  = ws + 5 * RD_;
    float* kbuf  = ws + 6 * RD_;
    float* vbuf  = ws + 7 * RD_;
    float* accb  = ws + 8 * RD_;     // VB_*D_*D_ = 4M floats

    const float inv_s  = 1.0f / (float)S_;
    const float inv_sd = 0.044194173824159216f;  // 1/sqrt(512)

    hipMemsetAsync(accb, 0, (size_t)VB_ * D_ * D_ * sizeof(float), stream);
    embed_kernel<<<R_, 128, 0, stream>>>(inputs, emb, state);

    for (int step = 0; step < STEPS_; step++) {
        // n = rms(state)
        rms_kernel<<<R_, 128, 0, stream>>>(state, nbuf);
        // g = sigmoid(n @ Wg)                       [32768,512]x[512,512]
        gemm_kernel<ACT_SIGMOID, false, false><<<dim3(256, 4, 1), 256, 0, stream>>>(
            nbuf, Wg, gbuf, nullptr, R_, D_, D_, 0, 0, 0, 1.0f, 0.0f);
        // u = gelu(n @ Wu)                          [32768,512]x[512,1024]
        gemm_kernel<ACT_GELU, false, false><<<dim3(256, 8, 1), 256, 0, stream>>>(
            nbuf, Wu, ubuf, nullptr, R_, 2 * D_, D_, 0, 0, 0, 1.0f, 0.0f);
        // state += g ⊙ (u @ Wd)                     [32768,1024]x[1024,512]
        gemm_kernel<ACT_IDENT, true, false><<<dim3(256, 4, 1), 256, 0, stream>>>(
            ubuf, Wd, state, gbuf, R_, D_, 2 * D_, 0, 0, 0, 1.0f, 1.0f);
        // n2 = rms(state)
        rms_kernel<<<R_, 128, 0, stream>>>(state, nbuf);
        // q = phi(n2 @ Wq); k = phi(n2 @ Wk); v = n2 @ Wv
        gemm_kernel<ACT_PHI, false, false><<<dim3(256, 4, 1), 256, 0, stream>>>(
            nbuf, Wq, qbuf, nullptr, R_, D_, D_, 0, 0, 0, 1.0f, 0.0f);
        gemm_kernel<ACT_PHI, false, false><<<dim3(256, 4, 1), 256, 0, stream>>>(
            nbuf, Wk, kbuf, nullptr, R_, D_, D_, 0, 0, 0, 1.0f, 0.0f);
        gemm_kernel<ACT_IDENT, false, false><<<dim3(256, 4, 1), 256, 0, stream>>>(
            nbuf, Wv, vbuf, nullptr, R_, D_, D_, 0, 0, 0, 1.0f, 0.0f);
        // acc = DECAY*acc + (k^T v)*inv_s           batched 16: [512,2048]^T x [2048,512]
        gemm_kernel<ACT_IDENT, false, true><<<dim3(4, 4, VB_), 256, 0, stream>>>(
            kbuf, vbuf, accb, nullptr, D_, D_, S_,
            (long)S_ * D_, (long)S_ * D_, (long)D_ * D_, inv_s, DECAY_);
        // mixed = (q @ acc) * inv_sqrt_d            batched 16: [2048,512]x[512,512]
        gemm_kernel<ACT_IDENT, false, false><<<dim3(16, 4, VB_), 256, 0, stream>>>(
            qbuf, accb, nbuf, nullptr, S_, D_, D_,
            (long)S_ * D_, (long)D_ * D_, (long)S_ * D_, inv_sd, 0.0f);
        // state += mixed @ Wo
        gemm_kernel<ACT_IDENT, false, false><<<dim3(256, 4, 1), 256, 0, stream>>>(
            nbuf, Wv_o, state, nullptr, R_, D_, D_, 0, 0, 0, 1.0f, 1.0f);
    }

    // combined = mean over views; rms in-place; logits = comb @ Wlm
    combine_kernel<<<(B_ * S_ * D_ / 4) / 256, 256, 0, stream>>>(state, gbuf);
    rms_kernel<<<B_ * S_, 128, 0, stream>>>(gbuf, gbuf);
    gemm_kernel<ACT_IDENT, false, false><<<dim3(128, 64, 1), 256, 0, stream>>>(
        gbuf, Wlm, out, nullptr, B_ * S_, VOCAB_, D_, 0, 0, 0, 1.0f, 0.0f);
}